// Round 10
// baseline (233.981 us; speedup 1.0000x reference)
//
#include <hip/hip_runtime.h>

// GCN 3-layer, bf16-MFMA GEMMs + bf16 CSR gather aggregation.
// Edge metadata packed: src (low 16b, N<65536) | bf16 weight (high 16b).

constexpr int D = 128;
constexpr int DOUT = 10;
constexpr int PSPLIT = 8;

using short8  = __attribute__((ext_vector_type(8))) short;
using float4v = __attribute__((ext_vector_type(4))) float;

__device__ __forceinline__ ushort f2bf(float f) {
  uint u = __float_as_uint(f);
  return (ushort)((u + 0x7fffu + ((u >> 16) & 1u)) >> 16);
}
__device__ __forceinline__ float bf2f(ushort s) {
  return __uint_as_float(((uint)s) << 16);
}
__device__ __forceinline__ float bflo(uint u) { return __uint_as_float(u << 16); }
__device__ __forceinline__ float bfhi(uint u) { return __uint_as_float(u & 0xffff0000u); }

// ---------------- setup kernels ----------------

__global__ void init_kernel(int* __restrict__ cnt, int n) {
  int i = blockIdx.x * blockDim.x + threadIdx.x;
  if (i < n) cnt[i] = 0;
}

__global__ void count_kernel(const int* __restrict__ dst, int* __restrict__ cnt, int e) {
  int i = blockIdx.x * blockDim.x + threadIdx.x;
  if (i < e) atomicAdd(&cnt[dst[i]], 1);
}

// hierarchical scan: (1) block sums, (2) scan sums, (3) per-block rescan + offset
__global__ __launch_bounds__(256) void scan1_kernel(const int* __restrict__ cnt,
    int* __restrict__ bsum, int n) {
  __shared__ int sd[256];
  int i = blockIdx.x * 256 + threadIdx.x;
  sd[threadIdx.x] = (i < n) ? cnt[i] : 0;
  __syncthreads();
  for (int off = 128; off > 0; off >>= 1) {
    if (threadIdx.x < (unsigned)off) sd[threadIdx.x] += sd[threadIdx.x + off];
    __syncthreads();
  }
  if (threadIdx.x == 0) bsum[blockIdx.x] = sd[0];
}

__global__ __launch_bounds__(1024) void scan2_kernel(const int* __restrict__ bsum,
    int* __restrict__ boff, int nb, int* __restrict__ rowptr, int n) {
  __shared__ int sd[1024];
  int v = ((int)threadIdx.x < nb) ? bsum[threadIdx.x] : 0;
  sd[threadIdx.x] = v;
  __syncthreads();
  for (int off = 1; off < 1024; off <<= 1) {
    int t = (threadIdx.x >= (unsigned)off) ? sd[threadIdx.x - off] : 0;
    __syncthreads();
    sd[threadIdx.x] += t;
    __syncthreads();
  }
  if ((int)threadIdx.x < nb) boff[threadIdx.x] = sd[threadIdx.x] - v;
  if ((int)threadIdx.x == nb - 1) rowptr[n] = sd[threadIdx.x];
}

__global__ __launch_bounds__(256) void scan3_kernel(const int* __restrict__ cnt,
    const int* __restrict__ boff, int* __restrict__ rowptr, int* __restrict__ cursor,
    float* __restrict__ dinv, int n) {
  __shared__ int sd[256];
  int i = blockIdx.x * 256 + threadIdx.x;
  int v = (i < n) ? cnt[i] : 0;
  sd[threadIdx.x] = v;
  __syncthreads();
  for (int off = 1; off < 256; off <<= 1) {
    int t = (threadIdx.x >= (unsigned)off) ? sd[threadIdx.x - off] : 0;
    __syncthreads();
    sd[threadIdx.x] += t;
    __syncthreads();
  }
  if (i < n) {
    int rp = boff[blockIdx.x] + sd[threadIdx.x] - v;
    rowptr[i] = rp;
    cursor[i] = rp;
    dinv[i] = rsqrtf((float)(v + 1));
  }
}

__global__ void fill_kernel(const int* __restrict__ src, const int* __restrict__ dst,
    int* __restrict__ cursor, const float* __restrict__ dinv,
    uint* __restrict__ epk, int e) {
  int i = blockIdx.x * blockDim.x + threadIdx.x;
  if (i < e) {
    int d = dst[i];
    int s = src[i];
    int slot = atomicAdd(&cursor[d], 1);
    epk[slot] = (uint)s | ((uint)f2bf(dinv[s] * dinv[d]) << 16);
  }
}

// ---------------- W[128][128] fp32 -> B-fragment-ordered bf16 (3 weights in one launch) ----------------
__global__ __launch_bounds__(256) void prepw_kernel(const float* __restrict__ W1,
    const float* __restrict__ W2, const float* __restrict__ W3, ushort* __restrict__ Wp) {
  const float* W = (blockIdx.y == 0) ? W1 : (blockIdx.y == 1) ? W2 : W3;
  ushort* Wpo = Wp + (size_t)blockIdx.y * 2048 * 8;
  int idx = blockIdx.x * 256 + threadIdx.x;  // 0..2047
  int cf = idx >> 8, kk = (idx >> 6) & 3, lane = idx & 63;
  int k0 = kk * 32 + (lane >> 4) * 8;
  int c = cf * 16 + (lane & 15);
  uint p[4];
  #pragma unroll
  for (int h = 0; h < 4; ++h) {
    ushort lo = f2bf(W[(k0 + 2 * h) * D + c]);
    ushort hi = f2bf(W[(k0 + 2 * h + 1) * D + c]);
    p[h] = (uint)lo | ((uint)hi << 16);
  }
  uint4 w = make_uint4(p[0], p[1], p[2], p[3]);
  *(uint4*)(Wpo + idx * 8) = w;
}

// ---------------- MFMA GEMM: out[n,128] bf16 = A[n,128] @ Wp ----------------
// F32 variant reads fp32 A and converts in-register (layer 1).
template<bool F32>
__global__ __launch_bounds__(256) void gemm_mfma(const void* __restrict__ Ain,
    const ushort* __restrict__ Wp, ushort* __restrict__ out, int n) {
  __shared__ ushort wl[2048 * 8];  // 32 KB, fragment-ordered W
  const int tid = threadIdx.x;
  #pragma unroll
  for (int i = 0; i < 8; ++i) {
    int idx = tid + i * 256;
    *(uint4*)(&wl[idx * 8]) = *(const uint4*)(Wp + idx * 8);
  }
  __syncthreads();
  const int w = tid >> 6, lane = tid & 63;
  const int row0 = blockIdx.x * 64 + w * 16;
  int arow = row0 + (lane & 15);
  if (arow >= n) arow = n - 1;

  short8 a[4];
  if constexpr (F32) {
    const float* abase = (const float*)Ain + (size_t)arow * D + ((lane >> 4) * 8);
    #pragma unroll
    for (int kk = 0; kk < 4; ++kk) {
      float4 f0 = *(const float4*)(abase + kk * 32);
      float4 f1 = *(const float4*)(abase + kk * 32 + 4);
      short8 v;
      v[0] = (short)f2bf(f0.x); v[1] = (short)f2bf(f0.y);
      v[2] = (short)f2bf(f0.z); v[3] = (short)f2bf(f0.w);
      v[4] = (short)f2bf(f1.x); v[5] = (short)f2bf(f1.y);
      v[6] = (short)f2bf(f1.z); v[7] = (short)f2bf(f1.w);
      a[kk] = v;
    }
  } else {
    const ushort* abase = (const ushort*)Ain + (size_t)arow * D + ((lane >> 4) * 8);
    #pragma unroll
    for (int kk = 0; kk < 4; ++kk) a[kk] = *(const short8*)(abase + kk * 32);
  }

  float4v acc[8] = {};
  #pragma unroll
  for (int kk = 0; kk < 4; ++kk) {
    #pragma unroll
    for (int cf = 0; cf < 8; ++cf) {
      short8 b = *(const short8*)(&wl[((cf * 4 + kk) * 64 + lane) * 8]);
      acc[cf] = __builtin_amdgcn_mfma_f32_16x16x32_bf16(a[kk], b, acc[cf], 0, 0, 0);
    }
  }
  const int crow = row0 + (lane >> 4) * 4;
  const int ccol = lane & 15;
  #pragma unroll
  for (int cf = 0; cf < 8; ++cf) {
    #pragma unroll
    for (int r = 0; r < 4; ++r) {
      if (crow + r < n) out[(size_t)(crow + r) * D + cf * 16 + ccol] = f2bf(acc[cf][r]);
    }
  }
}

// ---------------- aggregate: one wave per node, 2 edges/wave-load, 8-edge unroll ----------------
// lane = sub*32 + li: sub picks edge of pair, li covers 4 dims (uint2 = 4 bf16).
__global__ __launch_bounds__(256) void agg_kernel(const ushort* __restrict__ h,
    const int* __restrict__ rowptr, const uint* __restrict__ epk,
    const float* __restrict__ dinv, const float* __restrict__ bias,
    ushort* __restrict__ out, int n, int relu) {
  int node = (int)((blockIdx.x * blockDim.x + threadIdx.x) >> 6);
  if (node >= n) return;
  const int lane = threadIdx.x & 63;
  const int sub = lane >> 5;
  const int li = lane & 31;
  const int beg = rowptr[node], end = rowptr[node + 1];
  float a0 = 0.f, a1 = 0.f, a2 = 0.f, a3 = 0.f;
  for (int e = beg; e < end; e += 8) {
    int i0 = e + 0 + sub, i1 = e + 2 + sub, i2 = e + 4 + sub, i3 = e + 6 + sub;
    uint m0 = epk[min(i0, end - 1)];
    uint m1 = epk[min(i1, end - 1)];
    uint m2 = epk[min(i2, end - 1)];
    uint m3 = epk[min(i3, end - 1)];
    uint2 v0 = *(const uint2*)(h + (size_t)(m0 & 0xffffu) * D + li * 4);
    uint2 v1 = *(const uint2*)(h + (size_t)(m1 & 0xffffu) * D + li * 4);
    uint2 v2 = *(const uint2*)(h + (size_t)(m2 & 0xffffu) * D + li * 4);
    uint2 v3 = *(const uint2*)(h + (size_t)(m3 & 0xffffu) * D + li * 4);
    float w0 = (i0 < end) ? bfhi(m0) : 0.f;
    float w1 = (i1 < end) ? bfhi(m1) : 0.f;
    float w2 = (i2 < end) ? bfhi(m2) : 0.f;
    float w3 = (i3 < end) ? bfhi(m3) : 0.f;
    a0 += bflo(v0.x) * w0 + bflo(v1.x) * w1 + bflo(v2.x) * w2 + bflo(v3.x) * w3;
    a1 += bfhi(v0.x) * w0 + bfhi(v1.x) * w1 + bfhi(v2.x) * w2 + bfhi(v3.x) * w3;
    a2 += bflo(v0.y) * w0 + bflo(v1.y) * w1 + bflo(v2.y) * w2 + bflo(v3.y) * w3;
    a3 += bfhi(v0.y) * w0 + bfhi(v1.y) * w1 + bfhi(v2.y) * w2 + bfhi(v3.y) * w3;
  }
  // combine the two sub-halves
  a0 += __shfl_xor(a0, 32);
  a1 += __shfl_xor(a1, 32);
  a2 += __shfl_xor(a2, 32);
  a3 += __shfl_xor(a3, 32);
  // self loop + bias (identical in both halves)
  const float di = dinv[node];
  const float dsq = di * di;
  uint2 sv = *(const uint2*)(h + (size_t)node * D + li * 4);
  a0 += bflo(sv.x) * dsq;
  a1 += bfhi(sv.x) * dsq;
  a2 += bflo(sv.y) * dsq;
  a3 += bfhi(sv.y) * dsq;
  float4 bv = *(const float4*)(bias + li * 4);
  a0 += bv.x; a1 += bv.y; a2 += bv.z; a3 += bv.w;
  if (relu) {
    a0 = fmaxf(a0, 0.f); a1 = fmaxf(a1, 0.f);
    a2 = fmaxf(a2, 0.f); a3 = fmaxf(a3, 0.f);
  }
  if (sub == 0) {
    uint2 pk;
    pk.x = (uint)f2bf(a0) | ((uint)f2bf(a1) << 16);
    pk.y = (uint)f2bf(a2) | ((uint)f2bf(a3) << 16);
    *(uint2*)(out + (size_t)node * D + li * 4) = pk;
  }
}

// ---------------- pooling stage 1: grid (G, PSPLIT) ----------------
__global__ __launch_bounds__(256) void pool1_kernel(const ushort* __restrict__ act,
    const int* __restrict__ batch, float* __restrict__ pp, int n) {
  const int g = blockIdx.x;
  const int sp = blockIdx.y;
  int lo = 0, hi = n;
  while (lo < hi) { int mid = (lo + hi) >> 1; if (batch[mid] < g) lo = mid + 1; else hi = mid; }
  const int start = lo;
  hi = n;
  while (lo < hi) { int mid = (lo + hi) >> 1; if (batch[mid] <= g) lo = mid + 1; else hi = mid; }
  const int end = lo;
  const int len = end - start;
  const int per = (len + PSPLIT - 1) / PSPLIT;
  const int i0 = start + sp * per;
  const int i1 = min(i0 + per, end);

  const int rt = threadIdx.x >> 4;   // 0..15
  const int ds = threadIdx.x & 15;   // dim slice (8 dims each)
  float acc[8] = {};
  for (int i = i0 + rt; i < i1; i += 16) {
    short8 v = *(const short8*)(act + (size_t)i * D + ds * 8);
    #pragma unroll
    for (int e2 = 0; e2 < 8; ++e2) acc[e2] += bf2f((ushort)v[e2]);
  }
  __shared__ float sd[256][8];
  #pragma unroll
  for (int e2 = 0; e2 < 8; ++e2) sd[threadIdx.x][e2] = acc[e2];
  __syncthreads();
  if (threadIdx.x < 128) {
    int d = threadIdx.x;
    int slice = d >> 3, e2 = d & 7;
    float s = 0.f;
    #pragma unroll
    for (int k = 0; k < 16; ++k) s += sd[k * 16 + slice][e2];
    pp[((size_t)g * PSPLIT + sp) * D + d] = s;
  }
}

// ---------------- fused pool2 + head: mean, @Wl + bl, log_softmax ----------------
__global__ __launch_bounds__(640) void head_kernel(const float* __restrict__ pp,
    const int* __restrict__ batch, const float* __restrict__ Wl,
    const float* __restrict__ bl, float* __restrict__ out, int n, int g) {
  __shared__ float pooled[64 * D];   // 32 KB
  __shared__ float cnts[64];
  __shared__ float lg[64][DOUT];
  const int tid = threadIdx.x;
  if (tid < g) {
    int gg = tid;
    int lo = 0, hi = n;
    while (lo < hi) { int mid = (lo + hi) >> 1; if (batch[mid] < gg) lo = mid + 1; else hi = mid; }
    int start = lo;
    hi = n;
    while (lo < hi) { int mid = (lo + hi) >> 1; if (batch[mid] <= gg) lo = mid + 1; else hi = mid; }
    cnts[gg] = fmaxf((float)(lo - start), 1.f);
  }
  __syncthreads();
  for (int idx = tid; idx < g * D; idx += 640) {
    int gg = idx >> 7, d = idx & 127;
    float s = 0.f;
    #pragma unroll
    for (int sp = 0; sp < PSPLIT; ++sp) s += pp[((size_t)gg * PSPLIT + sp) * D + d];
    pooled[idx] = s / cnts[gg];
  }
  __syncthreads();
  int gi = tid / DOUT, o = tid % DOUT;
  if (gi < g) {
    float acc = bl[o];
    for (int d = 0; d < D; ++d) acc += pooled[gi * D + d] * Wl[d * DOUT + o];
    lg[gi][o] = acc;
  }
  __syncthreads();
  if (gi < g) {
    float m = -1e30f;
    for (int j = 0; j < DOUT; ++j) m = fmaxf(m, lg[gi][j]);
    float s = 0.f;
    for (int j = 0; j < DOUT; ++j) s += expf(lg[gi][j] - m);
    out[gi * DOUT + o] = lg[gi][o] - m - logf(s);
  }
}

// ---------------- launch ----------------

extern "C" void kernel_launch(void* const* d_in, const int* in_sizes, int n_in,
                              void* d_out, int out_size, void* d_ws, size_t ws_size,
                              hipStream_t stream) {
  const float* x   = (const float*)d_in[0];
  const int* src   = (const int*)d_in[1];
  const int* dst   = (const int*)d_in[2];
  const int* batch = (const int*)d_in[3];
  const float* W1  = (const float*)d_in[4];
  const float* b1  = (const float*)d_in[5];
  const float* W2  = (const float*)d_in[6];
  const float* b2  = (const float*)d_in[7];
  const float* W3  = (const float*)d_in[8];
  const float* b3  = (const float*)d_in[9];
  const float* Wl  = (const float*)d_in[10];
  const float* bl  = (const float*)d_in[11];
  float* out = (float*)d_out;

  const int n = in_sizes[0] / D;   // 50000
  const int e = in_sizes[1];       // 640000
  const int g = out_size / DOUT;   // 64

  char* p = (char*)d_ws;
  auto alloc = [&](size_t bytes) {
    char* r = p;
    p += (bytes + 255) & ~(size_t)255;
    return r;
  };
  const int nb = (n + 255) / 256;
  int* cnt      = (int*)alloc((size_t)n * 4);
  int* rowptr   = (int*)alloc((size_t)(n + 1) * 4);
  int* cursor   = (int*)alloc((size_t)n * 4);
  float* dinv   = (float*)alloc((size_t)n * 4);
  int* bsum     = (int*)alloc((size_t)nb * 4);
  int* boff     = (int*)alloc((size_t)nb * 4);
  uint* epk     = (uint*)alloc((size_t)e * 4);
  ushort* Wp    = (ushort*)alloc(3 * 2048 * 16);
  ushort* bfA   = (ushort*)alloc((size_t)n * D * 2);
  ushort* bfB   = (ushort*)alloc((size_t)n * D * 2);
  ushort* tmp   = (ushort*)alloc((size_t)n * D * 2);
  float* pp     = (float*)alloc((size_t)g * PSPLIT * D * 4);
  (void)ws_size;

  const int B = 256;
  const int gridN = (n + B - 1) / B;
  const int gridE = (e + B - 1) / B;

  init_kernel<<<gridN, B, 0, stream>>>(cnt, n);
  count_kernel<<<gridE, B, 0, stream>>>(dst, cnt, e);
  scan1_kernel<<<nb, B, 0, stream>>>(cnt, bsum, n);
  scan2_kernel<<<1, 1024, 0, stream>>>(bsum, boff, nb, rowptr, n);
  scan3_kernel<<<nb, B, 0, stream>>>(cnt, boff, rowptr, cursor, dinv, n);
  fill_kernel<<<gridE, B, 0, stream>>>(src, dst, cursor, dinv, epk, e);
  prepw_kernel<<<dim3(8, 3), B, 0, stream>>>(W1, W2, W3, Wp);

  const int gemmGrid = (n + 63) / 64;
  const int aggGrid = (n * 64 + B - 1) / B;

  // layer 1 (fp32 input, in-register convert)
  gemm_mfma<true><<<gemmGrid, B, 0, stream>>>(x, Wp, tmp, n);
  agg_kernel<<<aggGrid, B, 0, stream>>>(tmp, rowptr, epk, dinv, b1, bfB, n, 1);
  // layer 2
  gemm_mfma<false><<<gemmGrid, B, 0, stream>>>(bfB, Wp + 2048 * 8, tmp, n);
  agg_kernel<<<aggGrid, B, 0, stream>>>(tmp, rowptr, epk, dinv, b2, bfA, n, 1);
  // layer 3
  gemm_mfma<false><<<gemmGrid, B, 0, stream>>>(bfA, Wp + 2 * 2048 * 8, tmp, n);
  agg_kernel<<<aggGrid, B, 0, stream>>>(tmp, rowptr, epk, dinv, b3, bfB, n, 0);

  // pooling + fused head
  pool1_kernel<<<dim3(g, PSPLIT), B, 0, stream>>>(bfB, batch, pp, n);
  head_kernel<<<1, 640, 0, stream>>>(pp, batch, Wl, bl, out, n, g);
}

// Round 11
// 216.112 us; speedup vs baseline: 1.0827x; 1.0827x over previous
//
#include <hip/hip_runtime.h>

// GCN 3-layer, bf16-MFMA GEMMs; gathered intermediate (tmp) stored fp8 e4m3
// to halve aggregate-gather traffic. Activations stay bf16.
// Edge metadata packed: src (low 16b, N<65536) | bf16 weight (high 16b).

constexpr int D = 128;
constexpr int DOUT = 10;
constexpr int PSPLIT = 8;

using short8  = __attribute__((ext_vector_type(8))) short;
using float4v = __attribute__((ext_vector_type(4))) float;
using f32x2   = __attribute__((ext_vector_type(2))) float;

__device__ __forceinline__ ushort f2bf(float f) {
  uint u = __float_as_uint(f);
  return (ushort)((u + 0x7fffu + ((u >> 16) & 1u)) >> 16);
}
__device__ __forceinline__ float bf2f(ushort s) {
  return __uint_as_float(((uint)s) << 16);
}
__device__ __forceinline__ float bflo(uint u) { return __uint_as_float(u << 16); }
__device__ __forceinline__ float bfhi(uint u) { return __uint_as_float(u & 0xffff0000u); }

// ---------------- setup kernels ----------------

__global__ void init_kernel(int* __restrict__ cnt, int n) {
  int i = blockIdx.x * blockDim.x + threadIdx.x;
  if (i < n) cnt[i] = 0;
}

__global__ void count_kernel(const int* __restrict__ dst, int* __restrict__ cnt, int e) {
  int i = blockIdx.x * blockDim.x + threadIdx.x;
  if (i < e) atomicAdd(&cnt[dst[i]], 1);
}

// hierarchical scan: (1) block sums, (2) scan sums, (3) per-block rescan + offset
__global__ __launch_bounds__(256) void scan1_kernel(const int* __restrict__ cnt,
    int* __restrict__ bsum, int n) {
  __shared__ int sd[256];
  int i = blockIdx.x * 256 + threadIdx.x;
  sd[threadIdx.x] = (i < n) ? cnt[i] : 0;
  __syncthreads();
  for (int off = 128; off > 0; off >>= 1) {
    if (threadIdx.x < (unsigned)off) sd[threadIdx.x] += sd[threadIdx.x + off];
    __syncthreads();
  }
  if (threadIdx.x == 0) bsum[blockIdx.x] = sd[0];
}

__global__ __launch_bounds__(1024) void scan2_kernel(const int* __restrict__ bsum,
    int* __restrict__ boff, int nb, int* __restrict__ rowptr, int n) {
  __shared__ int sd[1024];
  int v = ((int)threadIdx.x < nb) ? bsum[threadIdx.x] : 0;
  sd[threadIdx.x] = v;
  __syncthreads();
  for (int off = 1; off < 1024; off <<= 1) {
    int t = (threadIdx.x >= (unsigned)off) ? sd[threadIdx.x - off] : 0;
    __syncthreads();
    sd[threadIdx.x] += t;
    __syncthreads();
  }
  if ((int)threadIdx.x < nb) boff[threadIdx.x] = sd[threadIdx.x] - v;
  if ((int)threadIdx.x == nb - 1) rowptr[n] = sd[threadIdx.x];
}

__global__ __launch_bounds__(256) void scan3_kernel(const int* __restrict__ cnt,
    const int* __restrict__ boff, int* __restrict__ rowptr, int* __restrict__ cursor,
    float* __restrict__ dinv, int n) {
  __shared__ int sd[256];
  int i = blockIdx.x * 256 + threadIdx.x;
  int v = (i < n) ? cnt[i] : 0;
  sd[threadIdx.x] = v;
  __syncthreads();
  for (int off = 1; off < 256; off <<= 1) {
    int t = (threadIdx.x >= (unsigned)off) ? sd[threadIdx.x - off] : 0;
    __syncthreads();
    sd[threadIdx.x] += t;
    __syncthreads();
  }
  if (i < n) {
    int rp = boff[blockIdx.x] + sd[threadIdx.x] - v;
    rowptr[i] = rp;
    cursor[i] = rp;
    dinv[i] = rsqrtf((float)(v + 1));
  }
}

__global__ void fill_kernel(const int* __restrict__ src, const int* __restrict__ dst,
    int* __restrict__ cursor, const float* __restrict__ dinv,
    uint* __restrict__ epk, int e) {
  int i = blockIdx.x * blockDim.x + threadIdx.x;
  if (i < e) {
    int d = dst[i];
    int s = src[i];
    int slot = atomicAdd(&cursor[d], 1);
    epk[slot] = (uint)s | ((uint)f2bf(dinv[s] * dinv[d]) << 16);
  }
}

// ---------------- W[128][128] fp32 -> B-fragment-ordered bf16 (3 weights in one launch) ----------------
__global__ __launch_bounds__(256) void prepw_kernel(const float* __restrict__ W1,
    const float* __restrict__ W2, const float* __restrict__ W3, ushort* __restrict__ Wp) {
  const float* W = (blockIdx.y == 0) ? W1 : (blockIdx.y == 1) ? W2 : W3;
  ushort* Wpo = Wp + (size_t)blockIdx.y * 2048 * 8;
  int idx = blockIdx.x * 256 + threadIdx.x;  // 0..2047
  int cf = idx >> 8, kk = (idx >> 6) & 3, lane = idx & 63;
  int k0 = kk * 32 + (lane >> 4) * 8;
  int c = cf * 16 + (lane & 15);
  uint p[4];
  #pragma unroll
  for (int h = 0; h < 4; ++h) {
    ushort lo = f2bf(W[(k0 + 2 * h) * D + c]);
    ushort hi = f2bf(W[(k0 + 2 * h + 1) * D + c]);
    p[h] = (uint)lo | ((uint)hi << 16);
  }
  uint4 w = make_uint4(p[0], p[1], p[2], p[3]);
  *(uint4*)(Wpo + idx * 8) = w;
}

// ---------------- MFMA GEMM: out[n,128] fp8 = A[n,128] @ Wp ----------------
// F32 variant reads fp32 A and converts in-register (layer 1).
template<bool F32>
__global__ __launch_bounds__(256) void gemm_mfma(const void* __restrict__ Ain,
    const ushort* __restrict__ Wp, uchar* __restrict__ out, int n) {
  __shared__ ushort wl[2048 * 8];  // 32 KB, fragment-ordered W
  const int tid = threadIdx.x;
  #pragma unroll
  for (int i = 0; i < 8; ++i) {
    int idx = tid + i * 256;
    *(uint4*)(&wl[idx * 8]) = *(const uint4*)(Wp + idx * 8);
  }
  __syncthreads();
  const int w = tid >> 6, lane = tid & 63;
  const int row0 = blockIdx.x * 64 + w * 16;
  int arow = row0 + (lane & 15);
  if (arow >= n) arow = n - 1;

  short8 a[4];
  if constexpr (F32) {
    const float* abase = (const float*)Ain + (size_t)arow * D + ((lane >> 4) * 8);
    #pragma unroll
    for (int kk = 0; kk < 4; ++kk) {
      float4 f0 = *(const float4*)(abase + kk * 32);
      float4 f1 = *(const float4*)(abase + kk * 32 + 4);
      short8 v;
      v[0] = (short)f2bf(f0.x); v[1] = (short)f2bf(f0.y);
      v[2] = (short)f2bf(f0.z); v[3] = (short)f2bf(f0.w);
      v[4] = (short)f2bf(f1.x); v[5] = (short)f2bf(f1.y);
      v[6] = (short)f2bf(f1.z); v[7] = (short)f2bf(f1.w);
      a[kk] = v;
    }
  } else {
    const ushort* abase = (const ushort*)Ain + (size_t)arow * D + ((lane >> 4) * 8);
    #pragma unroll
    for (int kk = 0; kk < 4; ++kk) a[kk] = *(const short8*)(abase + kk * 32);
  }

  float4v acc[8] = {};
  #pragma unroll
  for (int kk = 0; kk < 4; ++kk) {
    #pragma unroll
    for (int cf = 0; cf < 8; ++cf) {
      short8 b = *(const short8*)(&wl[((cf * 4 + kk) * 64 + lane) * 8]);
      acc[cf] = __builtin_amdgcn_mfma_f32_16x16x32_bf16(a[kk], b, acc[cf], 0, 0, 0);
    }
  }
  const int crow = row0 + (lane >> 4) * 4;
  const int ccol = lane & 15;
  #pragma unroll
  for (int cf = 0; cf < 8; ++cf) {
    #pragma unroll
    for (int r = 0; r < 4; ++r) {
      if (crow + r < n) {
        int enc = __builtin_amdgcn_cvt_pk_fp8_f32(acc[cf][r], acc[cf][r], 0, false);
        out[(size_t)(crow + r) * D + cf * 16 + ccol] = (uchar)(enc & 0xff);
      }
    }
  }
}

// ---------------- aggregate: one wave per node, fp8 rows, 8-edge unroll ----------------
// lane = sub*32 + li: sub picks edge of pair, li covers 4 dims (uint = 4 fp8).
__global__ __launch_bounds__(256) void agg_kernel(const uchar* __restrict__ h8,
    const int* __restrict__ rowptr, const uint* __restrict__ epk,
    const float* __restrict__ dinv, const float* __restrict__ bias,
    ushort* __restrict__ out, int n, int relu) {
  int node = (int)((blockIdx.x * blockDim.x + threadIdx.x) >> 6);
  if (node >= n) return;
  const int lane = threadIdx.x & 63;
  const int sub = lane >> 5;
  const int li = lane & 31;
  const int beg = rowptr[node], end = rowptr[node + 1];
  float a0 = 0.f, a1 = 0.f, a2 = 0.f, a3 = 0.f;
  for (int e = beg; e < end; e += 8) {
    int i0 = e + 0 + sub, i1 = e + 2 + sub, i2 = e + 4 + sub, i3 = e + 6 + sub;
    uint m0 = epk[min(i0, end - 1)];
    uint m1 = epk[min(i1, end - 1)];
    uint m2 = epk[min(i2, end - 1)];
    uint m3 = epk[min(i3, end - 1)];
    uint r0 = *(const uint*)(h8 + (size_t)(m0 & 0xffffu) * D + li * 4);
    uint r1 = *(const uint*)(h8 + (size_t)(m1 & 0xffffu) * D + li * 4);
    uint r2 = *(const uint*)(h8 + (size_t)(m2 & 0xffffu) * D + li * 4);
    uint r3 = *(const uint*)(h8 + (size_t)(m3 & 0xffffu) * D + li * 4);
    float w0 = (i0 < end) ? bfhi(m0) : 0.f;
    float w1 = (i1 < end) ? bfhi(m1) : 0.f;
    float w2 = (i2 < end) ? bfhi(m2) : 0.f;
    float w3 = (i3 < end) ? bfhi(m3) : 0.f;
    f32x2 p0a = __builtin_amdgcn_cvt_pk_f32_fp8(r0, false);
    f32x2 p0b = __builtin_amdgcn_cvt_pk_f32_fp8(r0, true);
    f32x2 p1a = __builtin_amdgcn_cvt_pk_f32_fp8(r1, false);
    f32x2 p1b = __builtin_amdgcn_cvt_pk_f32_fp8(r1, true);
    f32x2 p2a = __builtin_amdgcn_cvt_pk_f32_fp8(r2, false);
    f32x2 p2b = __builtin_amdgcn_cvt_pk_f32_fp8(r2, true);
    f32x2 p3a = __builtin_amdgcn_cvt_pk_f32_fp8(r3, false);
    f32x2 p3b = __builtin_amdgcn_cvt_pk_f32_fp8(r3, true);
    a0 += p0a[0] * w0 + p1a[0] * w1 + p2a[0] * w2 + p3a[0] * w3;
    a1 += p0a[1] * w0 + p1a[1] * w1 + p2a[1] * w2 + p3a[1] * w3;
    a2 += p0b[0] * w0 + p1b[0] * w1 + p2b[0] * w2 + p3b[0] * w3;
    a3 += p0b[1] * w0 + p1b[1] * w1 + p2b[1] * w2 + p3b[1] * w3;
  }
  // combine the two sub-halves
  a0 += __shfl_xor(a0, 32);
  a1 += __shfl_xor(a1, 32);
  a2 += __shfl_xor(a2, 32);
  a3 += __shfl_xor(a3, 32);
  // self loop + bias (identical in both halves)
  const float di = dinv[node];
  const float dsq = di * di;
  uint sv = *(const uint*)(h8 + (size_t)node * D + li * 4);
  f32x2 sa = __builtin_amdgcn_cvt_pk_f32_fp8(sv, false);
  f32x2 sb = __builtin_amdgcn_cvt_pk_f32_fp8(sv, true);
  a0 += sa[0] * dsq;
  a1 += sa[1] * dsq;
  a2 += sb[0] * dsq;
  a3 += sb[1] * dsq;
  float4 bv = *(const float4*)(bias + li * 4);
  a0 += bv.x; a1 += bv.y; a2 += bv.z; a3 += bv.w;
  if (relu) {
    a0 = fmaxf(a0, 0.f); a1 = fmaxf(a1, 0.f);
    a2 = fmaxf(a2, 0.f); a3 = fmaxf(a3, 0.f);
  }
  if (sub == 0) {
    uint2 pk;
    pk.x = (uint)f2bf(a0) | ((uint)f2bf(a1) << 16);
    pk.y = (uint)f2bf(a2) | ((uint)f2bf(a3) << 16);
    *(uint2*)(out + (size_t)node * D + li * 4) = pk;
  }
}

// ---------------- pooling stage 1: grid (G, PSPLIT) ----------------
__global__ __launch_bounds__(256) void pool1_kernel(const ushort* __restrict__ act,
    const int* __restrict__ batch, float* __restrict__ pp, int n) {
  const int g = blockIdx.x;
  const int sp = blockIdx.y;
  int lo = 0, hi = n;
  while (lo < hi) { int mid = (lo + hi) >> 1; if (batch[mid] < g) lo = mid + 1; else hi = mid; }
  const int start = lo;
  hi = n;
  while (lo < hi) { int mid = (lo + hi) >> 1; if (batch[mid] <= g) lo = mid + 1; else hi = mid; }
  const int end = lo;
  const int len = end - start;
  const int per = (len + PSPLIT - 1) / PSPLIT;
  const int i0 = start + sp * per;
  const int i1 = min(i0 + per, end);

  const int rt = threadIdx.x >> 4;   // 0..15
  const int ds = threadIdx.x & 15;   // dim slice (8 dims each)
  float acc[8] = {};
  for (int i = i0 + rt; i < i1; i += 16) {
    short8 v = *(const short8*)(act + (size_t)i * D + ds * 8);
    #pragma unroll
    for (int e2 = 0; e2 < 8; ++e2) acc[e2] += bf2f((ushort)v[e2]);
  }
  __shared__ float sd[256][8];
  #pragma unroll
  for (int e2 = 0; e2 < 8; ++e2) sd[threadIdx.x][e2] = acc[e2];
  __syncthreads();
  if (threadIdx.x < 128) {
    int d = threadIdx.x;
    int slice = d >> 3, e2 = d & 7;
    float s = 0.f;
    #pragma unroll
    for (int k = 0; k < 16; ++k) s += sd[k * 16 + slice][e2];
    pp[((size_t)g * PSPLIT + sp) * D + d] = s;
  }
}

// ---------------- fused pool2 + head: mean, @Wl + bl, log_softmax ----------------
__global__ __launch_bounds__(640) void head_kernel(const float* __restrict__ pp,
    const int* __restrict__ batch, const float* __restrict__ Wl,
    const float* __restrict__ bl, float* __restrict__ out, int n, int g) {
  __shared__ float pooled[64 * D];   // 32 KB
  __shared__ float cnts[64];
  __shared__ float lg[64][DOUT];
  const int tid = threadIdx.x;
  if (tid < g) {
    int gg = tid;
    int lo = 0, hi = n;
    while (lo < hi) { int mid = (lo + hi) >> 1; if (batch[mid] < gg) lo = mid + 1; else hi = mid; }
    int start = lo;
    hi = n;
    while (lo < hi) { int mid = (lo + hi) >> 1; if (batch[mid] <= gg) lo = mid + 1; else hi = mid; }
    cnts[gg] = fmaxf((float)(lo - start), 1.f);
  }
  __syncthreads();
  for (int idx = tid; idx < g * D; idx += 640) {
    int gg = idx >> 7, d = idx & 127;
    float s = 0.f;
    #pragma unroll
    for (int sp = 0; sp < PSPLIT; ++sp) s += pp[((size_t)gg * PSPLIT + sp) * D + d];
    pooled[idx] = s / cnts[gg];
  }
  __syncthreads();
  int gi = tid / DOUT, o = tid % DOUT;
  if (gi < g) {
    float acc = bl[o];
    for (int d = 0; d < D; ++d) acc += pooled[gi * D + d] * Wl[d * DOUT + o];
    lg[gi][o] = acc;
  }
  __syncthreads();
  if (gi < g) {
    float m = -1e30f;
    for (int j = 0; j < DOUT; ++j) m = fmaxf(m, lg[gi][j]);
    float s = 0.f;
    for (int j = 0; j < DOUT; ++j) s += expf(lg[gi][j] - m);
    out[gi * DOUT + o] = lg[gi][o] - m - logf(s);
  }
}

// ---------------- launch ----------------

extern "C" void kernel_launch(void* const* d_in, const int* in_sizes, int n_in,
                              void* d_out, int out_size, void* d_ws, size_t ws_size,
                              hipStream_t stream) {
  const float* x   = (const float*)d_in[0];
  const int* src   = (const int*)d_in[1];
  const int* dst   = (const int*)d_in[2];
  const int* batch = (const int*)d_in[3];
  const float* W1  = (const float*)d_in[4];
  const float* b1  = (const float*)d_in[5];
  const float* W2  = (const float*)d_in[6];
  const float* b2  = (const float*)d_in[7];
  const float* W3  = (const float*)d_in[8];
  const float* b3  = (const float*)d_in[9];
  const float* Wl  = (const float*)d_in[10];
  const float* bl  = (const float*)d_in[11];
  float* out = (float*)d_out;

  const int n = in_sizes[0] / D;   // 50000
  const int e = in_sizes[1];       // 640000
  const int g = out_size / DOUT;   // 64

  char* p = (char*)d_ws;
  auto alloc = [&](size_t bytes) {
    char* r = p;
    p += (bytes + 255) & ~(size_t)255;
    return r;
  };
  const int nb = (n + 255) / 256;
  int* cnt      = (int*)alloc((size_t)n * 4);
  int* rowptr   = (int*)alloc((size_t)(n + 1) * 4);
  int* cursor   = (int*)alloc((size_t)n * 4);
  float* dinv   = (float*)alloc((size_t)n * 4);
  int* bsum     = (int*)alloc((size_t)nb * 4);
  int* boff     = (int*)alloc((size_t)nb * 4);
  uint* epk     = (uint*)alloc((size_t)e * 4);
  ushort* Wp    = (ushort*)alloc(3 * 2048 * 16);
  ushort* bfA   = (ushort*)alloc((size_t)n * D * 2);
  ushort* bfB   = (ushort*)alloc((size_t)n * D * 2);
  uchar* tmp8   = (uchar*)alloc((size_t)n * D);
  float* pp     = (float*)alloc((size_t)g * PSPLIT * D * 4);
  (void)ws_size;

  const int B = 256;
  const int gridN = (n + B - 1) / B;
  const int gridE = (e + B - 1) / B;

  init_kernel<<<gridN, B, 0, stream>>>(cnt, n);
  count_kernel<<<gridE, B, 0, stream>>>(dst, cnt, e);
  scan1_kernel<<<nb, B, 0, stream>>>(cnt, bsum, n);
  scan2_kernel<<<1, 1024, 0, stream>>>(bsum, boff, nb, rowptr, n);
  scan3_kernel<<<nb, B, 0, stream>>>(cnt, boff, rowptr, cursor, dinv, n);
  fill_kernel<<<gridE, B, 0, stream>>>(src, dst, cursor, dinv, epk, e);
  prepw_kernel<<<dim3(8, 3), B, 0, stream>>>(W1, W2, W3, Wp);

  const int gemmGrid = (n + 63) / 64;
  const int aggGrid = (n * 64 + B - 1) / B;

  // layer 1 (fp32 input, in-register convert)
  gemm_mfma<true><<<gemmGrid, B, 0, stream>>>(x, Wp, tmp8, n);
  agg_kernel<<<aggGrid, B, 0, stream>>>(tmp8, rowptr, epk, dinv, b1, bfB, n, 1);
  // layer 2
  gemm_mfma<false><<<gemmGrid, B, 0, stream>>>(bfB, Wp + 2048 * 8, tmp8, n);
  agg_kernel<<<aggGrid, B, 0, stream>>>(tmp8, rowptr, epk, dinv, b2, bfA, n, 1);
  // layer 3
  gemm_mfma<false><<<gemmGrid, B, 0, stream>>>(bfA, Wp + 2 * 2048 * 8, tmp8, n);
  agg_kernel<<<aggGrid, B, 0, stream>>>(tmp8, rowptr, epk, dinv, b3, bfB, n, 0);

  // pooling + fused head
  pool1_kernel<<<dim3(g, PSPLIT), B, 0, stream>>>(bfB, batch, pp, n);
  head_kernel<<<1, 640, 0, stream>>>(pp, batch, Wl, bl, out, n, g);
}